// Round 4
// baseline (1051.476 us; speedup 1.0000x reference)
//
#include <hip/hip_runtime.h>
#include <hip/hip_bf16.h>
#include <hip/hip_cooperative_groups.h>

namespace cg = cooperative_groups;

typedef unsigned short ushortT;
typedef short short8 __attribute__((ext_vector_type(8)));
typedef unsigned short ushort8v __attribute__((ext_vector_type(8)));
typedef float float4v __attribute__((ext_vector_type(4)));

// Problem constants (from reference)
constexpr int Nn   = 20000;
constexpr int Ee   = 320000;
constexpr int EP   = Ee + Nn;     // edges + self loops
constexpr float NSL = 0.2f;       // leaky_relu negative slope
constexpr int CAP  = 128;         // per-dst bucket capacity

// ---------- helpers ----------
__device__ __forceinline__ float b2f(__hip_bfloat16 v) { return __bfloat162float(v); }
__device__ __forceinline__ float bits2f(unsigned short u) {
    __hip_bfloat16 b; *(unsigned short*)&b = u; return __bfloat162float(b);
}
__device__ __forceinline__ unsigned short f2bits(float v) {
    __hip_bfloat16 b = __float2bfloat16(v); return *(unsigned short*)&b;
}
__device__ __forceinline__ float ldf(const void* p, size_t i, int bf) {
    return bf ? __bfloat162float(((const __hip_bfloat16*)p)[i])
              : ((const float*)p)[i];
}
__device__ __forceinline__ void stf(void* p, size_t i, float v, int bf) {
    if (bf) ((__hip_bfloat16*)p)[i] = __float2bfloat16(v);
    else    ((float*)p)[i] = v;
}

// ---------- parameter block ----------
struct MP {
    const void* x; const int* ei;
    const void* W1; const void* as1; const void* ad1; const void* b1;
    const void* W2; const void* as2; const void* ad2; const void* b2;
    const void* W3; const void* as3; const void* ad3; const void* b3;
    const void* Wm; const void* bm; const void* Wv; const void* bv;
    ushortT* aggn; ushortT* xb; ushortT* x1b; ushortT* x2b; ushortT* h3;
    float* as_; float* ad_;
    ushortT* WT1c; ushortT* WT2c; float* wp1; float* wp2;
    int* cnt; int* csr; int* eflag; int* fflag;
    void* out;
};

// ---------- phase 0: setup (flags + cnt zero + W transposes + alpha projections) ----------
__device__ __forceinline__ int local_bf2(const unsigned* __restrict__ xbits, int* c_sh) {
    if (threadIdx.x == 0) *c_sh = 0;
    __syncthreads();
    int c = 0;
    for (int i = threadIdx.x; i < 512; i += 256) {
        unsigned e = (xbits[i] >> 7) & 0xFFu;
        if (e >= 110u && e <= 135u) ++c;
    }
    atomicAdd(c_sh, c);
    __syncthreads();
    int r = (*c_sh > 384) ? 1 : 0;
    __syncthreads();     // protect c_sh against re-init by a following call
    return r;
}

__device__ void setup_phase(const MP& p, int* sh_bad, int* sh_cs) {
    for (int vb = blockIdx.x; vb < 277; vb += gridDim.x) {
        if (vb < 79) {
            int gi = vb * 256 + threadIdx.x;
            if (gi < Nn) p.cnt[gi] = 0;
            if (vb == 0) {
                if (threadIdx.x == 0) *sh_bad = 0;
                __syncthreads();
                for (int i = threadIdx.x; i < 1024; i += 256)
                    if (p.ei[2 * i + 1] != 0) *sh_bad = 1;
                int bf = local_bf2((const unsigned*)p.x, sh_cs);
                if (threadIdx.x == 0) {
                    *p.eflag = (*sh_bad) ? 0 : 1;   // 1 => int64 edge_index layout
                    *p.fflag = bf;                  // 1 => floats delivered as bf16
                }
                __syncthreads();
            }
        } else if (vb < 271) {
            int bf = local_bf2((const unsigned*)p.x, sh_cs);
            int idx = (vb - 79) * 256 + threadIdx.x;       // 0..49151
            if (idx < 64 * 512) {
                int jp = idx >> 9, r = idx & 511, hh = r >> 7, k = r & 127;
                p.WT1c[idx] = f2bits(ldf(p.W1, (size_t)k * 256 + hh * 64 + jp, bf));
            } else {
                int i2 = idx - 64 * 512;                   // 0..16383
                int jp = i2 >> 8, r = i2 & 255, hh = r >> 6, k = r & 63;
                p.WT2c[i2] = f2bits(ldf(p.W2, (size_t)k * 256 + hh * 64 + jp, bf));
            }
        } else {
            int bf = local_bf2((const unsigned*)p.x, sh_cs);
            int idx = (vb - 271) * 256 + threadIdx.x;      // 0..1535
            if (idx < 1024) {
                int sd = idx >> 9, r = idx & 511, hh = r >> 7, k = r & 127;
                const void* av = sd ? p.ad1 : p.as1;
                float acc = 0.f;
                for (int c = 0; c < 64; ++c)
                    acc = fmaf(ldf(p.W1, (size_t)k * 256 + hh * 64 + c, bf),
                               ldf(av, hh * 64 + c, bf), acc);
                p.wp1[idx] = acc;
            } else if (idx < 1536) {
                int i2 = idx - 1024;
                int sd = i2 >> 8, r = i2 & 255, hh = r >> 6, k = r & 63;
                const void* av = sd ? p.ad2 : p.as2;
                float acc = 0.f;
                for (int c = 0; c < 64; ++c)
                    acc = fmaf(ldf(p.W2, (size_t)k * 256 + hh * 64 + c, bf),
                               ldf(av, hh * 64 + c, bf), acc);
                p.wp2[i2] = acc;
            }
        }
    }
}

// ---------- phase 1a: bucket scatter ----------
__device__ void scatter_phase(const MP& p) {
    const int gsz = gridDim.x * 256;
    const int sh = *p.eflag;
    for (int e = blockIdx.x * 256 + threadIdx.x; e < EP; e += gsz) {
        int si, di;
        if (e < Ee) {
            si = p.ei[(size_t)e << sh];
            di = p.ei[(size_t)(Ee + e) << sh];
        } else {
            si = di = e - Ee;   // self loop
        }
        int pos = atomicAdd(p.cnt + di, 1);
        if (pos < CAP) p.csr[di * CAP + pos] = si;
    }
}

// ---------- phase 1b: layer-1 alphas via projected weights + x -> bf16 cast ----------
__device__ void alpha1_phase(const MP& p) {
    const int bf = *p.fflag;
    const int cl = threadIdx.x & 31, g = threadIdx.x >> 5;
    const int c4 = cl * 4;
    for (int nb = blockIdx.x; nb < 2500; nb += gridDim.x) {
        const int n = nb * 8 + g;                     // < 20000 always
        float xv[4];
        if (bf) {
            ushort4 u = *(const ushort4*)((const ushortT*)p.x + (size_t)n * 128 + c4);
            xv[0] = bits2f(u.x); xv[1] = bits2f(u.y); xv[2] = bits2f(u.z); xv[3] = bits2f(u.w);
            *(ushort4*)(p.xb + (size_t)n * 128 + c4) = u;
        } else {
            float4 f = *(const float4*)((const float*)p.x + (size_t)n * 128 + c4);
            xv[0] = f.x; xv[1] = f.y; xv[2] = f.z; xv[3] = f.w;
            ushort4 u;
            u.x = f2bits(f.x); u.y = f2bits(f.y); u.z = f2bits(f.z); u.w = f2bits(f.w);
            *(ushort4*)(p.xb + (size_t)n * 128 + c4) = u;
        }
        float pr[8];
#pragma unroll
        for (int j = 0; j < 8; ++j) {
            float4 wv = *(const float4*)(p.wp1 + j * 128 + c4);
            float t = 0.f;
            t = fmaf(xv[0], wv.x, t);
            t = fmaf(xv[1], wv.y, t);
            t = fmaf(xv[2], wv.z, t);
            t = fmaf(xv[3], wv.w, t);
            pr[j] = t;
        }
#pragma unroll
        for (int off = 1; off < 32; off <<= 1) {
#pragma unroll
            for (int j = 0; j < 8; ++j) pr[j] += __shfl_xor(pr[j], off, 32);
        }
        if (cl == 0) {
            *(float4*)(p.as_ + (size_t)n * 4) = make_float4(pr[0], pr[1], pr[2], pr[3]);
            *(float4*)(p.ad_ + (size_t)n * 4) = make_float4(pr[4], pr[5], pr[6], pr[7]);
        }
    }
}

// ---------- per-edge eval helper ----------
__device__ __forceinline__ void edge_evals(const float* as_, int src, const float4& adv,
                                           float& s0, float& s1, float& s2, float& s3,
                                           float* slot) {
    float4 av = *(const float4*)(as_ + src * 4);
    float v0 = av.x + adv.x; v0 = v0 > 0.f ? v0 : NSL * v0; float e0 = __expf(v0);
    float v1 = av.y + adv.y; v1 = v1 > 0.f ? v1 : NSL * v1; float e1 = __expf(v1);
    float v2 = av.z + adv.z; v2 = v2 > 0.f ? v2 : NSL * v2; float e2 = __expf(v2);
    float v3 = av.w + adv.w; v3 = v3 > 0.f ? v3 : NSL * v3; float e3 = __expf(v3);
    s0 += e0; s1 += e1; s2 += e2; s3 += e3;
    *(float4*)slot = make_float4(e0, e1, e2, e3);
}

// ---------- phase 2: aggregate-first layer 1 (CIN=128), head-replicated gather ----------
__device__ void aggx128_phase(const MP& p, char* pool) {
    const int lane = threadIdx.x & 63, seg = threadIdx.x >> 6;
    float* lal_s = (float*)pool + seg * (CAP * 4);
    for (int db = blockIdx.x; db < 5000; db += gridDim.x) {
        const int d = db * 4 + seg;                  // < 20000 always
        const int deg = min(p.cnt[d], CAP);
        const int base = d * CAP;
        const float4 adv = *(const float4*)(p.ad_ + d * 4);
        const int src0 = (lane < deg) ? p.csr[base + lane] : 0;
        const int src1 = (64 + lane < deg) ? p.csr[base + 64 + lane] : 0;
        float s0 = 0, s1 = 0, s2 = 0, s3 = 0;
        if (lane < deg)      edge_evals(p.as_, src0, adv, s0, s1, s2, s3, lal_s + lane * 4);
        if (64 + lane < deg) edge_evals(p.as_, src1, adv, s0, s1, s2, s3, lal_s + (64 + lane) * 4);
        const int q = lane >> 4, c8 = (lane & 15) * 8;
        float a[8] = {0, 0, 0, 0, 0, 0, 0, 0};
        auto do_edge = [&](int idx) {
            int sa = __shfl(src0, idx & 63, 64);
            int sb = __shfl(src1, idx & 63, 64);
            int src = (idx < 64) ? sa : sb;
            float ev = lal_s[idx * 4 + q];
            ushort8v xv = *(const ushort8v*)(p.xb + (size_t)src * 128 + c8);
#pragma unroll
            for (int j = 0; j < 8; ++j) a[j] = fmaf(ev, bits2f(xv[j]), a[j]);
        };
        int e = 0;
        for (; e + 4 <= deg; e += 4) {
            do_edge(e); do_edge(e + 1); do_edge(e + 2); do_edge(e + 3);
        }
        for (; e < deg; ++e) do_edge(e);
#pragma unroll
        for (int off = 1; off < 64; off <<= 1) {
            s0 += __shfl_xor(s0, off, 64);
            s1 += __shfl_xor(s1, off, 64);
            s2 += __shfl_xor(s2, off, 64);
            s3 += __shfl_xor(s3, off, 64);
        }
        const float sq = (q == 0) ? s0 : (q == 1) ? s1 : (q == 2) ? s2 : s3;
        const float iq = 0.25f / (sq + 1e-16f);
        ushort8v pk;
#pragma unroll
        for (int j = 0; j < 8; ++j) pk[j] = f2bits(a[j] * iq);
        *(ushort8v*)(p.aggn + (size_t)d * 512 + q * 128 + c8) = pk;
    }
}

// ---------- phase 4: aggregate-first layer 2 (CIN=64) ----------
__device__ void aggx64_phase(const MP& p, char* pool) {
    const int lane = threadIdx.x & 63, seg = threadIdx.x >> 6;
    float* lal_s = (float*)pool + seg * (CAP * 4);
    for (int db = blockIdx.x; db < 5000; db += gridDim.x) {
        const int d = db * 4 + seg;
        const int deg = min(p.cnt[d], CAP);
        const int base = d * CAP;
        const float4 adv = *(const float4*)(p.ad_ + d * 4);
        const int src0 = (lane < deg) ? p.csr[base + lane] : 0;
        const int src1 = (64 + lane < deg) ? p.csr[base + 64 + lane] : 0;
        float s0 = 0, s1 = 0, s2 = 0, s3 = 0;
        if (lane < deg)      edge_evals(p.as_, src0, adv, s0, s1, s2, s3, lal_s + lane * 4);
        if (64 + lane < deg) edge_evals(p.as_, src1, adv, s0, s1, s2, s3, lal_s + (64 + lane) * 4);
        const int hl = lane >> 5, cl = lane & 31;
        const int q = cl >> 3, c8 = (cl & 7) * 8;
        float a[8] = {0, 0, 0, 0, 0, 0, 0, 0};
        auto do_edge = [&](int idx, bool valid) {
            int sa = __shfl(src0, idx & 63, 64);
            int sb = __shfl(src1, idx & 63, 64);
            int src = (idx < 64) ? sa : sb;
            float ev = valid ? lal_s[idx * 4 + q] : 0.0f;
            int off = valid ? src * 64 : 0;
            ushort8v xv = *(const ushort8v*)(p.x1b + (size_t)off + c8);
#pragma unroll
            for (int j = 0; j < 8; ++j) a[j] = fmaf(ev, bits2f(xv[j]), a[j]);
        };
        int e = 0;
        for (; e + 8 <= deg; e += 8) {
            do_edge(e + hl, true);
            do_edge(e + 2 + hl, true);
            do_edge(e + 4 + hl, true);
            do_edge(e + 6 + hl, true);
        }
        for (; e < deg; e += 2) do_edge(e + hl, (e + hl) < deg);
#pragma unroll
        for (int off = 1; off < 64; off <<= 1) {
            s0 += __shfl_xor(s0, off, 64);
            s1 += __shfl_xor(s1, off, 64);
            s2 += __shfl_xor(s2, off, 64);
            s3 += __shfl_xor(s3, off, 64);
        }
#pragma unroll
        for (int j = 0; j < 8; ++j) a[j] += __shfl_xor(a[j], 32, 64);
        const float sq = (q == 0) ? s0 : (q == 1) ? s1 : (q == 2) ? s2 : s3;
        const float iq = 0.25f / (sq + 1e-16f);
        if (hl == 0) {
            ushort8v pk;
#pragma unroll
            for (int j = 0; j < 8; ++j) pk[j] = f2bits(a[j] * iq);
            *(ushort8v*)(p.aggn + (size_t)d * 256 + q * 64 + c8) = pk;
        }
    }
}

// ---------- phases 3/5: post-aggregation transform (MFMA), fused next-layer alphas ----------
template <int K, int NPROJ>
__device__ void cat_phase(const MP& p, const ushortT* WTc, const void* bias,
                          const float* wp, ushortT* xout, char* pool) {
    constexpr int KC = 128, SW = KC + 8, NCH = K / KC;
    ushortT* wt_s = (ushortT*)pool;                       // 17408 B
    ushortT* xs   = (ushortT*)(pool + 17408);             // 17408 B
    float*   wp_s = (float*)(pool + 34816);               // 2048 B
    const int bf = *p.fflag;
    const int lane = threadIdx.x & 63, w = threadIdx.x >> 6;
    const int ln = lane & 15, quad = lane >> 4;
    for (int bb = blockIdx.x; bb < 313; bb += gridDim.x) {
        const int base = bb * 64;
        float4v acc[4];
#pragma unroll
        for (int T = 0; T < 4; ++T) acc[T] = (float4v){0.f, 0.f, 0.f, 0.f};
        if (NPROJ) {
            for (int i = threadIdx.x; i < NPROJ * 64; i += 256) wp_s[i] = wp[i];
        }
#pragma unroll
        for (int ch = 0; ch < NCH; ++ch) {
            for (int i = threadIdx.x; i < 64 * 16; i += 256) {
                int r = i >> 4, kc = (i & 15) * 8;
                *(short8*)(wt_s + r * SW + kc) =
                    *(const short8*)(WTc + (size_t)r * K + ch * KC + kc);
                int node = base + r;
                short8 v = {0, 0, 0, 0, 0, 0, 0, 0};
                if (node < Nn) v = *(const short8*)(p.aggn + (size_t)node * K + ch * KC + kc);
                *(short8*)(xs + r * SW + kc) = v;
            }
            __syncthreads();
#pragma unroll
            for (int ks = 0; ks < 4; ++ks) {
                const int kb = ks * 32 + quad * 8;
                const short8 bfr = *(const short8*)(xs + (w * 16 + ln) * SW + kb);
#pragma unroll
                for (int T = 0; T < 4; ++T) {
                    const short8 afr = *(const short8*)(wt_s + (T * 16 + ln) * SW + kb);
                    acc[T] = __builtin_amdgcn_mfma_f32_16x16x32_bf16(afr, bfr, acc[T], 0, 0, 0);
                }
            }
            __syncthreads();
        }
        const int node = base + w * 16 + ln;
        const bool live = node < Nn;
        ushortT* on = xout + (size_t)node * 64;
        float pr[8];
#pragma unroll
        for (int j = 0; j < 8; ++j) pr[j] = 0.f;
#pragma unroll
        for (int T = 0; T < 4; ++T) {
            const int jl = T * 16 + quad * 4;
            ushort4 pk;
            float t0 = fmaxf(acc[T][0] + ldf(bias, jl + 0, bf), 0.f);
            float t1 = fmaxf(acc[T][1] + ldf(bias, jl + 1, bf), 0.f);
            float t2 = fmaxf(acc[T][2] + ldf(bias, jl + 2, bf), 0.f);
            float t3 = fmaxf(acc[T][3] + ldf(bias, jl + 3, bf), 0.f);
            pk.x = f2bits(t0); pk.y = f2bits(t1); pk.z = f2bits(t2); pk.w = f2bits(t3);
            if (live) *(ushort4*)(on + jl) = pk;
            if (NPROJ) {
#pragma unroll
                for (int j = 0; j < 8; ++j) {
                    pr[j] = fmaf(t0, wp_s[j * 64 + jl + 0], pr[j]);
                    pr[j] = fmaf(t1, wp_s[j * 64 + jl + 1], pr[j]);
                    pr[j] = fmaf(t2, wp_s[j * 64 + jl + 2], pr[j]);
                    pr[j] = fmaf(t3, wp_s[j * 64 + jl + 3], pr[j]);
                }
            }
        }
        if (NPROJ) {
#pragma unroll
            for (int j = 0; j < 8; ++j) {
                pr[j] += __shfl_xor(pr[j], 16, 64);
                pr[j] += __shfl_xor(pr[j], 32, 64);
            }
            if (quad == 0 && live) {
                *(float4*)(p.as_ + (size_t)node * 4) = make_float4(pr[0], pr[1], pr[2], pr[3]);
                *(float4*)(p.ad_ + (size_t)node * 4) = make_float4(pr[4], pr[5], pr[6], pr[7]);
            }
        }
        __syncthreads();    // protect LDS reuse across bb iterations
    }
}

// ---------- phase 6: small GEMM (layer 3), bf16 input, fused alphas ----------
__device__ void small_phase(const MP& p, char* pool) {
    constexpr int INC = 64, R = 32, PAD = R + 4;
    float* xsh = (float*)pool;                            // 9216 B
    const int bf = *p.fflag;
    const int jc = threadIdx.x & 31;
    const int g  = threadIdx.x >> 5;
    for (int bb = blockIdx.x; bb < 625; bb += gridDim.x) {
        int base = bb * R;
        for (int i = threadIdx.x; i < R * INC; i += 256) {
            int rr = i / INC, kk = i - rr * INC;
            int nn = base + rr;
            xsh[kk * PAD + rr] = (nn < Nn) ? bits2f(p.x2b[(size_t)nn * INC + kk]) : 0.0f;
        }
        __syncthreads();
        float acc[4] = {};
        if (bf) {
            const __hip_bfloat16* Wb = (const __hip_bfloat16*)p.W3;
#pragma unroll 4
            for (int k = 0; k < INC; ++k) {
                float4 xv = *(const float4*)(xsh + k * PAD + g * 4);
                float w = b2f(Wb[k * 32 + jc]);
                acc[0] = fmaf(xv.x, w, acc[0]);
                acc[1] = fmaf(xv.y, w, acc[1]);
                acc[2] = fmaf(xv.z, w, acc[2]);
                acc[3] = fmaf(xv.w, w, acc[3]);
            }
        } else {
            const float* Wf = (const float*)p.W3;
#pragma unroll 4
            for (int k = 0; k < INC; ++k) {
                float4 xv = *(const float4*)(xsh + k * PAD + g * 4);
                float w = Wf[k * 32 + jc];
                acc[0] = fmaf(xv.x, w, acc[0]);
                acc[1] = fmaf(xv.y, w, acc[1]);
                acc[2] = fmaf(xv.z, w, acc[2]);
                acc[3] = fmaf(xv.w, w, acc[3]);
            }
        }
        float avsr = ldf(p.as3, jc, bf), avdr = ldf(p.ad3, jc, bf);
#pragma unroll
        for (int m = 0; m < 4; ++m) {
            int n = base + g * 4 + m;
            if (n < Nn) {
                p.h3[(size_t)n * 32 + jc] = f2bits(acc[m]);
                float t1 = acc[m] * avsr;
                float t2 = acc[m] * avdr;
#pragma unroll
                for (int off = 16; off > 0; off >>= 1) {
                    t1 += __shfl_down(t1, off, 32);
                    t2 += __shfl_down(t2, off, 32);
                }
                if (jc == 0) { p.as_[n] = t1; p.ad_[n] = t2; }
            }
        }
        __syncthreads();    // protect xsh reuse across bb iterations
    }
}

// ---------- phase 7: layer-3 aggregation fused with output heads ----------
__device__ void aggr1f_phase(const MP& p, char* pool) {
    float* wm_s = (float*)pool;                           // 4096 B
    float* wv_s = (float*)(pool + 4096);                  // 4096 B
    float* lalp = (float*)(pool + 8192);                  // 4096 B
    int*   lofp = (int*)(pool + 12288);                   // 4096 B
    const int bf = *p.fflag;
    for (int i = threadIdx.x; i < 1024; i += 256) {
        wm_s[i] = ldf(p.Wm, i, bf);
        wv_s[i] = ldf(p.Wv, i, bf);
    }
    __syncthreads();
    const int c = threadIdx.x & 31, seg = threadIdx.x >> 5;
    float* lal = lalp + seg * CAP;
    int*   lof = lofp + seg * CAP;
    for (int bb = blockIdx.x; bb < 2500; bb += gridDim.x) {
        const int d = bb * 8 + seg;                       // < 20000 always
        const int deg = min(p.cnt[d], CAP);
        const int base = d * CAP;
        const float advd = p.ad_[d];
        float s = 0;
        for (int i = c; i < deg; i += 32) {
            int src = p.csr[base + i];
            float v = p.as_[src] + advd;
            v = v > 0.f ? v : NSL * v;
            float ev = __expf(v);
            s += ev;
            lal[i] = ev;
            lof[i] = src * 32;
        }
        float acc = 0.0f;
        int e = 0;
        for (; e + 4 <= deg; e += 4) {
            float ev0 = lal[e], ev1 = lal[e + 1];
            float ev2 = lal[e + 2], ev3 = lal[e + 3];
            int o0 = lof[e], o1 = lof[e + 1];
            int o2 = lof[e + 2], o3 = lof[e + 3];
            float h0 = bits2f(p.h3[o0 + c]), h1 = bits2f(p.h3[o1 + c]);
            float h2 = bits2f(p.h3[o2 + c]), h3v = bits2f(p.h3[o3 + c]);
            acc = fmaf(ev0, h0, acc);
            acc = fmaf(ev1, h1, acc);
            acc = fmaf(ev2, h2, acc);
            acc = fmaf(ev3, h3v, acc);
        }
        for (; e < deg; ++e) acc = fmaf(lal[e], bits2f(p.h3[lof[e] + c]), acc);
#pragma unroll
        for (int off = 1; off < 32; off <<= 1) s += __shfl_xor(s, off, 32);
        const float inv = 1.0f / (s + 1e-16f);
        const float z = inv * acc + ldf(p.b3, c, bf);
        stf(p.out, (size_t)2 * Nn * 32 + (size_t)d * 32 + c, z, bf);   // z
        float sm = ldf(p.bm, c, bf), sv = ldf(p.bv, c, bf);
#pragma unroll 8
        for (int k = 0; k < 32; ++k) {
            float zk = __shfl(z, k, 32);
            sm = fmaf(zk, wm_s[k * 32 + c], sm);
            sv = fmaf(zk, wv_s[k * 32 + c], sv);
        }
        float var = __expf(sv);
        var = fminf(fmaxf(var, 1e-8f), 100.0f);
        stf(p.out, (size_t)d * 32 + c, sm, bf);                        // z_mean
        stf(p.out, (size_t)Nn * 32 + (size_t)d * 32 + c, var, bf);     // z_var
    }
}

// ---------- the single cooperative mega-kernel ----------
__global__ __launch_bounds__(256, 4) void mega_k(MP p) {
    __shared__ __align__(16) char pool[36864];
    __shared__ int sh_bad, sh_cs;
    cg::grid_group grid = cg::this_grid();

    setup_phase(p, &sh_bad, &sh_cs);
    __threadfence(); grid.sync();

    scatter_phase(p);
    alpha1_phase(p);
    __threadfence(); grid.sync();

    aggx128_phase(p, pool);
    __threadfence(); grid.sync();

    cat_phase<512, 8>(p, p.WT1c, p.b1, p.wp2, p.x1b, pool);
    __threadfence(); grid.sync();

    aggx64_phase(p, pool);
    __threadfence(); grid.sync();

    cat_phase<256, 0>(p, p.WT2c, p.b2, nullptr, p.x2b, pool);
    __threadfence(); grid.sync();

    small_phase(p, pool);
    __threadfence(); grid.sync();

    aggr1f_phase(p, pool);
}

// ---------- fallback wrappers (same phase bodies, separate dispatches) ----------
__global__ __launch_bounds__(256) void w_setup(MP p) {
    __shared__ int a, b; setup_phase(p, &a, &b);
}
__global__ __launch_bounds__(256) void w_scatter(MP p) { scatter_phase(p); }
__global__ __launch_bounds__(256) void w_alpha1(MP p) { alpha1_phase(p); }
__global__ __launch_bounds__(256) void w_aggx128(MP p) {
    __shared__ __align__(16) char pool[8192]; aggx128_phase(p, pool);
}
__global__ __launch_bounds__(256) void w_aggx64(MP p) {
    __shared__ __align__(16) char pool[8192]; aggx64_phase(p, pool);
}
template <int K, int NPROJ>
__global__ __launch_bounds__(256) void w_cat(MP p, const ushortT* WTc, const void* bias,
                                             const float* wp, ushortT* xout) {
    __shared__ __align__(16) char pool[36864]; cat_phase<K, NPROJ>(p, WTc, bias, wp, xout, pool);
}
__global__ __launch_bounds__(256) void w_small(MP p) {
    __shared__ __align__(16) char pool[9216]; small_phase(p, pool);
}
__global__ __launch_bounds__(256) void w_aggr1f(MP p) {
    __shared__ __align__(16) char pool[16384]; aggr1f_phase(p, pool);
}

// ---------- launch ----------
extern "C" void kernel_launch(void* const* d_in, const int* in_sizes, int n_in,
                              void* d_out, int out_size, void* d_ws, size_t ws_size,
                              hipStream_t stream) {
    float* ws = (float*)d_ws;
    MP p;
    p.x   = d_in[0];  p.ei  = (const int*)d_in[1];
    p.W1  = d_in[2];  p.as1 = d_in[3];  p.ad1 = d_in[4];  p.b1 = d_in[5];
    p.W2  = d_in[6];  p.as2 = d_in[7];  p.ad2 = d_in[8];  p.b2 = d_in[9];
    p.W3  = d_in[10]; p.as3 = d_in[11]; p.ad3 = d_in[12]; p.b3 = d_in[13];
    p.Wm  = d_in[14]; p.bm  = d_in[15]; p.Wv  = d_in[16]; p.bv = d_in[17];
    p.aggn = (ushortT*)ws;                    // 20000*512 bf16 = 5,120,000 floats
    p.xb   = (ushortT*)(ws + 5120000);        // 20000*128 bf16
    p.x1b  = (ushortT*)(ws + 6400000);        // 20000*64 bf16
    p.x2b  = (ushortT*)(ws + 7040000);        // 20000*64 bf16
    p.h3   = (ushortT*)(ws + 7680000);        // 20000*32 bf16
    p.as_  = ws + 8000000;                    // 80,000
    p.ad_  = ws + 8080000;                    // 80,000
    p.WT1c = (ushortT*)(ws + 8160000);        // 64*512 bf16
    p.WT2c = (ushortT*)(ws + 8176384);        // 64*256 bf16
    p.wp1  = ws + 8184576;                    // 1,024
    p.wp2  = ws + 8185600;                    // 512
    p.cnt  = (int*)(ws + 8186112);            // 20,000
    p.csr  = (int*)(ws + 8206112);            // 2,560,000
    p.eflag = (int*)(ws + 10766112);
    p.fflag = (int*)(ws + 10766113);
    p.out  = d_out;

    static int s_grid = 0;
    if (s_grid == 0) {
        int perCU = 0, ncu = 0;
        if (hipOccupancyMaxActiveBlocksPerMultiprocessor(&perCU, mega_k, 256, 0) != hipSuccess)
            perCU = 0;
        if (hipDeviceGetAttribute(&ncu, hipDeviceAttributeMultiprocessorCount, 0) != hipSuccess
            || ncu < 1)
            ncu = 256;
        s_grid = (perCU >= 1) ? perCU * ncu : -1;
        if (s_grid > 5000) s_grid = 5000;
        if (s_grid > 0 && s_grid < 280) s_grid = -1;   // need >=277 for setup coverage margin
    }

    bool coop_ok = false;
    if (s_grid > 0) {
        void* args[] = { (void*)&p };
        hipError_t err = hipLaunchCooperativeKernel((const void*)mega_k,
                                                    dim3(s_grid), dim3(256),
                                                    args, 0, stream);
        coop_ok = (err == hipSuccess);
    }
    if (!coop_ok) {
        w_setup<<<277, 256, 0, stream>>>(p);
        w_scatter<<<(EP + 255) / 256, 256, 0, stream>>>(p);
        w_alpha1<<<2500, 256, 0, stream>>>(p);
        w_aggx128<<<5000, 256, 0, stream>>>(p);
        w_cat<512, 8><<<313, 256, 0, stream>>>(p, p.WT1c, p.b1, p.wp2, p.x1b);
        w_aggx64<<<5000, 256, 0, stream>>>(p);
        w_cat<256, 0><<<313, 256, 0, stream>>>(p, p.WT2c, p.b2, nullptr, p.x2b);
        w_small<<<625, 256, 0, stream>>>(p);
        w_aggr1f<<<2500, 256, 0, stream>>>(p);
    }
}